// Round 10
// baseline (447.509 us; speedup 1.0000x reference)
//
#include <hip/hip_runtime.h>
#include <stdint.h>

typedef unsigned short u16;
typedef unsigned int   u32;
typedef __attribute__((ext_vector_type(8))) __bf16 bf16x8;
typedef __attribute__((ext_vector_type(4))) float  f32x4;

#define MFMA_16x16x32_BF16(a, b, c) __builtin_amdgcn_mfma_f32_16x16x32_bf16((a), (b), (c), 0, 0, 0)

__device__ __forceinline__ u16 f2b(float f) {
    u32 u = __builtin_bit_cast(u32, f);
    u32 r = (u + 0x7FFFu + ((u >> 16) & 1u)) >> 16;
    return (u16)r;
}
__device__ __forceinline__ float b2f(u16 h) {
    u32 u = ((u32)h) << 16;
    return __builtin_bit_cast(float, u);
}

// async 16B per lane global->LDS; dest is wave-uniform base + lane*16
__device__ __forceinline__ void gload_lds16(const void* g, void* l) {
    __builtin_amdgcn_global_load_lds(
        (const __attribute__((address_space(1))) u32*)g,
        (__attribute__((address_space(3))) u32*)l,
        16, 0, 0);
}

// ---------------------------------------------------------------------------
// Stage 1: fp32 -> bf16 casts (x, w_qkv, w_proj), grid-stride float4 lanes
// ---------------------------------------------------------------------------
__global__ __launch_bounds__(256) void cast3(const float* __restrict__ x,
                                             const float* __restrict__ wq,
                                             const float* __restrict__ wp,
                                             u16* __restrict__ xb,
                                             u16* __restrict__ wqb,
                                             u16* __restrict__ wpb) {
    const int n1 = 8388608, n2 = 12582912, n3 = 4194304;
    const int total4 = (n1 + n2 + n3) / 4;
    for (int i = blockIdx.x * blockDim.x + threadIdx.x; i < total4;
         i += gridDim.x * blockDim.x) {
        int e = i * 4;
        const float* src; u16* dst; int off;
        if (e < n1)            { src = x;  dst = xb;  off = e; }
        else if (e < n1 + n2)  { src = wq; dst = wqb; off = e - n1; }
        else                   { src = wp; dst = wpb; off = e - n1 - n2; }
        float4 v = *(const float4*)(src + off);
        ushort4 o;
        o.x = f2b(v.x); o.y = f2b(v.y); o.z = f2b(v.z); o.w = f2b(v.w);
        *(ushort4*)(dst + off) = o;
    }
}

// ---------------------------------------------------------------------------
// Stage 2/6: C = A * Bt^T (bf16 in, fp32 acc), 128x128 tile, BK=64, 256 thr,
// XOR-swizzled LDS. Keeper (873 TF); 256^2 4-phase line closed (717 TF).
// ---------------------------------------------------------------------------
template <int OUT_BF16>
__global__ __launch_bounds__(256) void gemm_bt(const u16* __restrict__ A,
                                               const u16* __restrict__ Bt,
                                               void* __restrict__ Cout,
                                               int M, int N, int K) {
    __shared__ u16 Al[128 * 64];
    __shared__ u16 Bl[128 * 64];
    const int tid  = threadIdx.x;
    const int w    = tid >> 6;
    const int lane = tid & 63;
    const int quad = lane >> 4;
    const int l16  = lane & 15;
    const int m0 = blockIdx.y * 128;
    const int n0 = blockIdx.x * 128;
    const int wm = (w >> 1) * 64;
    const int wn = (w & 1) * 64;

    f32x4 acc[4][4];
#pragma unroll
    for (int i = 0; i < 4; i++) {
#pragma unroll
        for (int j = 0; j < 4; j++) acc[i][j] = (f32x4){0.f, 0.f, 0.f, 0.f};
    }

    const int srow = tid >> 3;
    const int scol = ((tid & 7) ^ (srow & 7)) * 8;
    const u16* Abase = A + (size_t)(m0 + srow) * K + scol;
    const u16* Bbase = Bt + (size_t)(n0 + srow) * K + scol;
    char* AlB = (char*)Al + w * 1024;
    char* BlB = (char*)Bl + w * 1024;
    const int fx = (l16 & 7);

    for (int k0 = 0; k0 < K; k0 += 64) {
        __syncthreads();
#pragma unroll
        for (int i = 0; i < 4; i++) {
            gload_lds16(Abase + (size_t)i * 32 * K + k0, AlB + i * 4096);
            gload_lds16(Bbase + (size_t)i * 32 * K + k0, BlB + i * 4096);
        }
        __syncthreads();
#pragma unroll
        for (int ks = 0; ks < 2; ks++) {
            const int cb = ((ks * 4 + quad) ^ fx) * 8;
            bf16x8 Af[4];
#pragma unroll
            for (int mi = 0; mi < 4; mi++)
                Af[mi] = *(const bf16x8*)&Al[(wm + mi * 16 + l16) * 64 + cb];
#pragma unroll
            for (int ni = 0; ni < 4; ni++) {
                bf16x8 Bf = *(const bf16x8*)&Bl[(wn + ni * 16 + l16) * 64 + cb];
#pragma unroll
                for (int mi = 0; mi < 4; mi++)
                    acc[mi][ni] = MFMA_16x16x32_BF16(Af[mi], Bf, acc[mi][ni]);
            }
        }
    }

    const int row0 = m0 + wm + quad * 4;
    const int col0 = n0 + wn + l16;
#pragma unroll
    for (int mi = 0; mi < 4; mi++) {
#pragma unroll
        for (int r = 0; r < 4; r++) {
            size_t rowb = (size_t)(row0 + mi * 16 + r) * N;
#pragma unroll
            for (int ni = 0; ni < 4; ni++) {
                float v = acc[mi][ni][r];
                if (OUT_BF16) ((u16*)Cout)[rowb + col0 + ni * 16] = f2b(v);
                else          ((float*)Cout)[rowb + col0 + ni * 16] = v;
            }
        }
    }
}

// ---------------------------------------------------------------------------
// Stage 3: RoPE (vectorized): one 8-elem chunk per thread, 16B load/store,
// shared 64-entry cos/sin table. 256 thr = 2 qk x 16 h x 8 chunks.
// ---------------------------------------------------------------------------
__global__ __launch_bounds__(256) void rope_qk(const u16* __restrict__ qkv,
                                               u16* __restrict__ Q,
                                               u16* __restrict__ K) {
    __shared__ float cs[64], sn[64];
    const int bt = blockIdx.x;          // 0..4095
    const int b = bt >> 11, t = bt & 2047;
    const u16* row = qkv + (size_t)bt * 6144;
    const int tid = threadIdx.x;

    if (tid < 64) {
        float inv = __expf(-0.14391156f * (float)tid);   // 10000^(-tid/64)
        float s, c;
        sincosf((float)t * inv, &s, &c);
        sn[tid] = s; cs[tid] = c;
    }
    __syncthreads();

    const int qk = tid >> 7;            // 0=q, 1=k
    const int h  = (tid >> 3) & 15;
    const int i0 = (tid & 7) * 8;
    const u16* src = row + qk * 2048 + h * 128;
    uint4 a  = *(const uint4*)(src + i0);        // x1 chunk
    uint4 b4 = *(const uint4*)(src + i0 + 64);   // x2 chunk
    const u16* pa = (const u16*)&a;
    const u16* pb = (const u16*)&b4;
    u16 o1[8], o2[8];
#pragma unroll
    for (int j = 0; j < 8; j++) {
        int i = i0 + j;
        float x1 = b2f(pa[j]), x2 = b2f(pb[j]);
        float s = sn[i], c = cs[i];
        o1[j] = f2b(x1 * c - x2 * s);
        o2[j] = f2b(x2 * c + x1 * s);
    }
    u16* dst = (qk ? K : Q) + ((size_t)((b * 16 + h) * 2048 + t)) * 128;
    *(uint4*)(dst + i0)      = *(uint4*)o1;
    *(uint4*)(dst + i0 + 64) = *(uint4*)o2;
}

// ---------------------------------------------------------------------------
// Stage 4: V transpose: qkv v-slice -> VT[B,H,Dh,T]; grid (32 tc, 32 bh)
// ---------------------------------------------------------------------------
__global__ __launch_bounds__(256) void vtrans(const u16* __restrict__ qkv,
                                              u16* __restrict__ VT) {
    __shared__ u16 S[64 * 136];         // [t][d], padded stride 136
    const int tc = blockIdx.x;
    const int bh = blockIdx.y;
    const int b = bh >> 4, h = bh & 15;
    const int tid = threadIdx.x;

#pragma unroll
    for (int i = 0; i < 4; i++) {
        int idx = i * 256 + tid;
        int t  = idx >> 4;
        int d8 = (idx & 15) * 8;
        uint4 v = *(const uint4*)(qkv + ((size_t)(b * 2048 + tc * 64 + t)) * 6144
                                      + 4096 + h * 128 + d8);
        *(uint4*)&S[t * 136 + d8] = v;
    }
    __syncthreads();
#pragma unroll
    for (int i = 0; i < 4; i++) {
        int idx = i * 256 + tid;
        int d  = idx >> 3;
        int t8 = (idx & 7) * 8;
        u16 tmp[8];
#pragma unroll
        for (int j = 0; j < 8; j++) tmp[j] = S[(t8 + j) * 136 + d];
        *(uint4*)(VT + ((size_t)(bh * 128 + d)) * 2048 + tc * 64 + t8) = *(uint4*)tmp;
    }
}

// ---------------------------------------------------------------------------
// Stage 5: causal flash attention v8: fine-grained blocks for TLP.
// Back-computed budget shows attn ~160us (largest kernel) at only ~210 TF;
// r6 (half traffic, half waves -> net 0) says it's latency/serial-chain
// bound, not LDS-throughput bound. Fix: q-tile 32 (2 waves), KVBLK 32,
// balanced pairing {p, 63-p} -> 65 kt/block, grid (32,32)=1024 blocks,
// LDS 34.5KB -> 4 resident blocks/CU: same 8 waves/CU but in 4
// barrier-INDEPENDENT blocks with half-length per-kt critical paths.
// Swizzles: K/P identical math; V granule swizzle p^((row>>1)&3) for the
// 64B-row tile (<=2-way per 16-lane phase, same class as gemm's measured-0).
// Closed lines: 2-wave/KVBLK64 (r6), V direct-global (r7, 4x overfetch).
// ---------------------------------------------------------------------------
__global__ __launch_bounds__(128, 2) void attn(const u16* __restrict__ Q,
                                               const u16* __restrict__ Kg,
                                               const u16* __restrict__ VTg,
                                               u16* __restrict__ O) {
    __shared__ u16 Kl[2][32 * 128];     // [buf][key][d], XOR-swizzled (16KB)
    __shared__ u16 Vt[2][128 * 32];     // [buf][d][key], XOR-swizzled (16KB)
    __shared__ u16 Pl[2 * 16 * 40];     // per-wave P[q][key], stride 40 (2.5KB)

    const int tid  = threadIdx.x;
    const int w    = tid >> 6;          // 0..1
    const int lane = tid & 63;
    const int quad = lane >> 4;
    const int l16  = lane & 15;
    const int p    = blockIdx.x;        // 0..31 (pair index)
    const int bh   = blockIdx.y;        // 0..31
    const int b = bh >> 4, h = bh & 15;
    const size_t base = (size_t)bh * 2048 * 128;
    const u16* Qb  = Q + base;
    const u16* Kb  = Kg + base;
    const u16* VTb = VTg + base;        // [128 d][2048 t]
    u16* Plw = Pl + w * 16 * 40;
    const float scale = 0.08838834764831845f;   // 1/sqrt(128)

    // K staging (32x128 tile, 4 issues x 8 rows): pos (row, c) holds
    // global granule c^(row&7); row = i*8 + (tid>>4)
    const int krow = tid >> 4;                          // 0..7
    const int kcol = (((tid & 15) ^ (krow & 7)) * 8);   // u16 units
    // V staging (128x32 tile, 4 issues x 32 rows): pos (row, c) holds
    // global granule c^((row>>1)&3); row = i*32 + (tid>>2)
    const int vrow = tid >> 2;                          // 0..31
    const int vcol = (((tid & 3) ^ ((vrow >> 1) & 3)) * 8);
    const int fx   = (l16 & 7);                         // K fragment swizzle
    const int px   = ((l16 >> 1) & 3);                  // V fragment swizzle

    for (int s = 0; s < 2; s++) {
        const int qt   = s ? (63 - p) : p;      // 32-row q-tile index, 0..63
        const int q0   = qt * 32;
        const int row0 = q0 + w * 16;           // this wave's first q row

        // Q fragments (B operand of S^T MFMA)
        bf16x8 Qf[4];
#pragma unroll
        for (int kk = 0; kk < 4; kk++)
            Qf[kk] = *(const bf16x8*)&Qb[(size_t)(row0 + l16) * 128 + kk * 32 + quad * 8];

        f32x4 Oacc[8];
#pragma unroll
        for (int ni = 0; ni < 8; ni++) Oacc[ni] = (f32x4){0.f, 0.f, 0.f, 0.f};
        float mrow = -1e30f, lrow = 0.f;        // per-lane state (q = row0+l16)

        const int nkt = qt + 1;                 // 32-key tiles to cover diag

        __syncthreads();    // protect buf0 from the previous s-iteration
        {
            const u16* ksrc = Kb + (size_t)krow * 128 + kcol;
            char* kdst = (char*)Kl[0] + w * 1024;
            const u16* vsrc = VTb + (size_t)vrow * 2048 + vcol;
            char* vdst = (char*)Vt[0] + w * 1024;
#pragma unroll
            for (int i = 0; i < 4; i++) {
                gload_lds16(ksrc + (size_t)i * 8 * 128, kdst + i * 2048);
                gload_lds16(vsrc + (size_t)i * 32 * 2048, vdst + i * 2048);
            }
        }

        for (int kt = 0; kt < nkt; kt++) {
            const int kt0 = kt * 32;
            const int cur = kt & 1;
            __syncthreads();    // drains async loads + syncs the 2 waves

            if (kt + 1 < nkt) {
                const int kt1 = kt0 + 32;
                const u16* ksrc = Kb + (size_t)(kt1 + krow) * 128 + kcol;
                char* kdst = (char*)Kl[cur ^ 1] + w * 1024;
                const u16* vsrc = VTb + (size_t)vrow * 2048 + kt1 + vcol;
                char* vdst = (char*)Vt[cur ^ 1] + w * 1024;
#pragma unroll
                for (int i = 0; i < 4; i++) {
                    gload_lds16(ksrc + (size_t)i * 8 * 128, kdst + i * 2048);
                    gload_lds16(vsrc + (size_t)i * 32 * 2048, vdst + i * 2048);
                }
            }

            const u16* Klc = Kl[cur];
            const u16* Vtc = Vt[cur];

            // S^T = K Q^T: D[key][q], q = l16, key = mi*16 + quad*4 + r
            f32x4 ST[2];
#pragma unroll
            for (int mi = 0; mi < 2; mi++) ST[mi] = (f32x4){0.f, 0.f, 0.f, 0.f};
#pragma unroll
            for (int kk = 0; kk < 4; kk++) {
                const int cb = ((kk * 4 + quad) ^ fx) * 8;
#pragma unroll
                for (int mi = 0; mi < 2; mi++) {
                    bf16x8 Kf = *(const bf16x8*)&Klc[(mi * 16 + l16) * 128 + cb];
                    ST[mi] = MFMA_16x16x32_BF16(Kf, Qf[kk], ST[mi]);
                }
            }

            // scale + causal mask (diagonal tiles only)
            const bool needs_mask = (kt0 + 31) > row0;
            const int qg = row0 + l16;
            float tmax = -1e30f;
#pragma unroll
            for (int mi = 0; mi < 2; mi++) {
#pragma unroll
                for (int r = 0; r < 4; r++) {
                    float sv = ST[mi][r] * scale;
                    if (needs_mask) {
                        int kg = kt0 + mi * 16 + quad * 4 + r;
                        sv = (kg > qg) ? -1e30f : sv;
                    }
                    ST[mi][r] = sv;
                    tmax = fmaxf(tmax, sv);
                }
            }
            tmax = fmaxf(tmax, __shfl_xor(tmax, 16));
            tmax = fmaxf(tmax, __shfl_xor(tmax, 32));

            // T13 defer-max: only rescale O when some row's max grew by > 8
            if (__any(tmax > mrow + 8.0f)) {
                float mnew  = fmaxf(mrow, tmax);
                float alpha = __expf(mrow - mnew);
                mrow = mnew;
                lrow *= alpha;
                float aRow[4];
#pragma unroll
                for (int r = 0; r < 4; r++) aRow[r] = __shfl(alpha, quad * 4 + r);
#pragma unroll
                for (int ni = 0; ni < 8; ni++) {
#pragma unroll
                    for (int r = 0; r < 4; r++) Oacc[ni][r] *= aRow[r];
                }
            }

            float tsum = 0.f;
#pragma unroll
            for (int mi = 0; mi < 2; mi++) {
#pragma unroll
                for (int r = 0; r < 4; r++) {
                    float p2 = __expf(ST[mi][r] - mrow);
                    ST[mi][r] = p2;
                    tsum += p2;
                }
            }
            lrow += tsum;

            // P[q][key] -> LDS (b64 packs, padded stride 40)
#pragma unroll
            for (int mi = 0; mi < 2; mi++) {
                ushort4 pk;
                pk.x = f2b(ST[mi][0]); pk.y = f2b(ST[mi][1]);
                pk.z = f2b(ST[mi][2]); pk.w = f2b(ST[mi][3]);
                *(ushort4*)&Plw[l16 * 40 + mi * 16 + quad * 4] = pk;
            }

            // O += P V (single kk step: MFMA K-depth 32 == KVBLK)
            bf16x8 Pf = *(const bf16x8*)&Plw[l16 * 40 + quad * 8];
#pragma unroll
            for (int ni = 0; ni < 8; ni++) {
                bf16x8 Vf = *(const bf16x8*)&Vtc[(ni * 16 + l16) * 32 + (quad ^ px) * 8];
                Oacc[ni] = MFMA_16x16x32_BF16(Pf, Vf, Oacc[ni]);
            }
        }

        // final normalization: reduce per-lane partials across quads
        lrow += __shfl_xor(lrow, 16);
        lrow += __shfl_xor(lrow, 32);
        float inv = 1.0f / lrow;
        float iRow[4];
#pragma unroll
        for (int r = 0; r < 4; r++) iRow[r] = __shfl(inv, quad * 4 + r);

#pragma unroll
        for (int r = 0; r < 4; r++) {
            int t = row0 + quad * 4 + r;
            size_t rowb = ((size_t)(b * 2048 + t)) * 2048 + (size_t)(h * 128);
#pragma unroll
            for (int ni = 0; ni < 8; ni++)
                O[rowb + ni * 16 + l16] = f2b(Oacc[ni][r] * iRow[r]);
        }
    }
}

// ---------------------------------------------------------------------------
extern "C" void kernel_launch(void* const* d_in, const int* in_sizes, int n_in,
                              void* d_out, int out_size, void* d_ws, size_t ws_size,
                              hipStream_t stream) {
    const float* x  = (const float*)d_in[0];
    const float* wq = (const float*)d_in[1];
    const float* wp = (const float*)d_in[2];

    char* ws = (char*)d_ws;
    u16* xb   = (u16*)(ws + 0);            // 16,777,216 B
    u16* wqb  = (u16*)(ws + 16777216);     // 25,165,824 B
    u16* wpb  = (u16*)(ws + 41943040);     //  8,388,608 B
    u16* qkvb = (u16*)(ws + 50331648);     // 50,331,648 B
    u16* Qr   = (u16*)(ws + 100663296);    // 16,777,216 B
    u16* Kr   = (u16*)(ws + 117440512);    // 16,777,216 B
    u16* VTt  = (u16*)(ws + 134217728);    // 16,777,216 B (V^T, [B,H,Dh,T])
    u16* Ob   = (u16*)(ws + 50331648);     // overlays qkvb (dead after rope/vtrans)
    if (ws_size < 150994944) return;

    cast3<<<2048, 256, 0, stream>>>(x, wq, wp, xb, wqb, wpb);
    gemm_bt<1><<<dim3(48, 32), 256, 0, stream>>>(xb, wqb, qkvb, 4096, 6144, 2048);
    rope_qk<<<4096, 256, 0, stream>>>(qkvb, Qr, Kr);
    vtrans<<<dim3(32, 32), 256, 0, stream>>>(qkvb, VTt);
    attn<<<dim3(32, 32), 128, 0, stream>>>(Qr, Kr, VTt, Ob);
    gemm_bt<0><<<dim3(16, 32), 256, 0, stream>>>(Ob, wpb, (float*)d_out, 4096, 2048, 2048);
}

// Round 11
// 384.392 us; speedup vs baseline: 1.1642x; 1.1642x over previous
//
#include <hip/hip_runtime.h>
#include <stdint.h>

typedef unsigned short u16;
typedef unsigned int   u32;
typedef __attribute__((ext_vector_type(8))) __bf16 bf16x8;
typedef __attribute__((ext_vector_type(4))) float  f32x4;

#define MFMA_16x16x32_BF16(a, b, c) __builtin_amdgcn_mfma_f32_16x16x32_bf16((a), (b), (c), 0, 0, 0)

__device__ __forceinline__ u16 f2b(float f) {
    u32 u = __builtin_bit_cast(u32, f);
    u32 r = (u + 0x7FFFu + ((u >> 16) & 1u)) >> 16;
    return (u16)r;
}
__device__ __forceinline__ float b2f(u16 h) {
    u32 u = ((u32)h) << 16;
    return __builtin_bit_cast(float, u);
}

// async 16B per lane global->LDS; dest is wave-uniform base + lane*16
__device__ __forceinline__ void gload_lds16(const void* g, void* l) {
    __builtin_amdgcn_global_load_lds(
        (const __attribute__((address_space(1))) u32*)g,
        (__attribute__((address_space(3))) u32*)l,
        16, 0, 0);
}

// ---------------------------------------------------------------------------
// Stage 1: fp32 -> bf16 casts (x, w_qkv, w_proj), grid-stride float4 lanes
// ---------------------------------------------------------------------------
__global__ __launch_bounds__(256) void cast3(const float* __restrict__ x,
                                             const float* __restrict__ wq,
                                             const float* __restrict__ wp,
                                             u16* __restrict__ xb,
                                             u16* __restrict__ wqb,
                                             u16* __restrict__ wpb) {
    const int n1 = 8388608, n2 = 12582912, n3 = 4194304;
    const int total4 = (n1 + n2 + n3) / 4;
    for (int i = blockIdx.x * blockDim.x + threadIdx.x; i < total4;
         i += gridDim.x * blockDim.x) {
        int e = i * 4;
        const float* src; u16* dst; int off;
        if (e < n1)            { src = x;  dst = xb;  off = e; }
        else if (e < n1 + n2)  { src = wq; dst = wqb; off = e - n1; }
        else                   { src = wp; dst = wpb; off = e - n1 - n2; }
        float4 v = *(const float4*)(src + off);
        ushort4 o;
        o.x = f2b(v.x); o.y = f2b(v.y); o.z = f2b(v.z); o.w = f2b(v.w);
        *(ushort4*)(dst + off) = o;
    }
}

// ---------------------------------------------------------------------------
// Stage 2/6: C = A * Bt^T (bf16 in, fp32 acc), 128x128 tile, BK=64, 256 thr,
// XOR-swizzled LDS. Keeper (873 TF); 256^2 4-phase line closed (717 TF).
// ---------------------------------------------------------------------------
template <int OUT_BF16>
__global__ __launch_bounds__(256) void gemm_bt(const u16* __restrict__ A,
                                               const u16* __restrict__ Bt,
                                               void* __restrict__ Cout,
                                               int M, int N, int K) {
    __shared__ u16 Al[128 * 64];
    __shared__ u16 Bl[128 * 64];
    const int tid  = threadIdx.x;
    const int w    = tid >> 6;
    const int lane = tid & 63;
    const int quad = lane >> 4;
    const int l16  = lane & 15;
    const int m0 = blockIdx.y * 128;
    const int n0 = blockIdx.x * 128;
    const int wm = (w >> 1) * 64;
    const int wn = (w & 1) * 64;

    f32x4 acc[4][4];
#pragma unroll
    for (int i = 0; i < 4; i++) {
#pragma unroll
        for (int j = 0; j < 4; j++) acc[i][j] = (f32x4){0.f, 0.f, 0.f, 0.f};
    }

    const int srow = tid >> 3;
    const int scol = ((tid & 7) ^ (srow & 7)) * 8;
    const u16* Abase = A + (size_t)(m0 + srow) * K + scol;
    const u16* Bbase = Bt + (size_t)(n0 + srow) * K + scol;
    char* AlB = (char*)Al + w * 1024;
    char* BlB = (char*)Bl + w * 1024;
    const int fx = (l16 & 7);

    for (int k0 = 0; k0 < K; k0 += 64) {
        __syncthreads();
#pragma unroll
        for (int i = 0; i < 4; i++) {
            gload_lds16(Abase + (size_t)i * 32 * K + k0, AlB + i * 4096);
            gload_lds16(Bbase + (size_t)i * 32 * K + k0, BlB + i * 4096);
        }
        __syncthreads();
#pragma unroll
        for (int ks = 0; ks < 2; ks++) {
            const int cb = ((ks * 4 + quad) ^ fx) * 8;
            bf16x8 Af[4];
#pragma unroll
            for (int mi = 0; mi < 4; mi++)
                Af[mi] = *(const bf16x8*)&Al[(wm + mi * 16 + l16) * 64 + cb];
#pragma unroll
            for (int ni = 0; ni < 4; ni++) {
                bf16x8 Bf = *(const bf16x8*)&Bl[(wn + ni * 16 + l16) * 64 + cb];
#pragma unroll
                for (int mi = 0; mi < 4; mi++)
                    acc[mi][ni] = MFMA_16x16x32_BF16(Af[mi], Bf, acc[mi][ni]);
            }
        }
    }

    const int row0 = m0 + wm + quad * 4;
    const int col0 = n0 + wn + l16;
#pragma unroll
    for (int mi = 0; mi < 4; mi++) {
#pragma unroll
        for (int r = 0; r < 4; r++) {
            size_t rowb = (size_t)(row0 + mi * 16 + r) * N;
#pragma unroll
            for (int ni = 0; ni < 4; ni++) {
                float v = acc[mi][ni][r];
                if (OUT_BF16) ((u16*)Cout)[rowb + col0 + ni * 16] = f2b(v);
                else          ((float*)Cout)[rowb + col0 + ni * 16] = v;
            }
        }
    }
}

// ---------------------------------------------------------------------------
// Stage 3: RoPE (vectorized): one 8-elem chunk per thread, 16B load/store,
// shared 64-entry cos/sin table. 256 thr = 2 qk x 16 h x 8 chunks.
// ---------------------------------------------------------------------------
__global__ __launch_bounds__(256) void rope_qk(const u16* __restrict__ qkv,
                                               u16* __restrict__ Q,
                                               u16* __restrict__ K) {
    __shared__ float cs[64], sn[64];
    const int bt = blockIdx.x;          // 0..4095
    const int b = bt >> 11, t = bt & 2047;
    const u16* row = qkv + (size_t)bt * 6144;
    const int tid = threadIdx.x;

    if (tid < 64) {
        float inv = __expf(-0.14391156f * (float)tid);   // 10000^(-tid/64)
        float s, c;
        sincosf((float)t * inv, &s, &c);
        sn[tid] = s; cs[tid] = c;
    }
    __syncthreads();

    const int qk = tid >> 7;            // 0=q, 1=k
    const int h  = (tid >> 3) & 15;
    const int i0 = (tid & 7) * 8;
    const u16* src = row + qk * 2048 + h * 128;
    uint4 a  = *(const uint4*)(src + i0);        // x1 chunk
    uint4 b4 = *(const uint4*)(src + i0 + 64);   // x2 chunk
    const u16* pa = (const u16*)&a;
    const u16* pb = (const u16*)&b4;
    u16 o1[8], o2[8];
#pragma unroll
    for (int j = 0; j < 8; j++) {
        int i = i0 + j;
        float x1 = b2f(pa[j]), x2 = b2f(pb[j]);
        float s = sn[i], c = cs[i];
        o1[j] = f2b(x1 * c - x2 * s);
        o2[j] = f2b(x2 * c + x1 * s);
    }
    u16* dst = (qk ? K : Q) + ((size_t)((b * 16 + h) * 2048 + t)) * 128;
    *(uint4*)(dst + i0)      = *(uint4*)o1;
    *(uint4*)(dst + i0 + 64) = *(uint4*)o2;
}

// ---------------------------------------------------------------------------
// Stage 4: V transpose: qkv v-slice -> VT[B,H,Dh,T]; grid (32 tc, 32 bh)
// ---------------------------------------------------------------------------
__global__ __launch_bounds__(256) void vtrans(const u16* __restrict__ qkv,
                                              u16* __restrict__ VT) {
    __shared__ u16 S[64 * 136];         // [t][d], padded stride 136
    const int tc = blockIdx.x;
    const int bh = blockIdx.y;
    const int b = bh >> 4, h = bh & 15;
    const int tid = threadIdx.x;

#pragma unroll
    for (int i = 0; i < 4; i++) {
        int idx = i * 256 + tid;
        int t  = idx >> 4;
        int d8 = (idx & 15) * 8;
        uint4 v = *(const uint4*)(qkv + ((size_t)(b * 2048 + tc * 64 + t)) * 6144
                                      + 4096 + h * 128 + d8);
        *(uint4*)&S[t * 136 + d8] = v;
    }
    __syncthreads();
#pragma unroll
    for (int i = 0; i < 4; i++) {
        int idx = i * 256 + tid;
        int d  = idx >> 3;
        int t8 = (idx & 7) * 8;
        u16 tmp[8];
#pragma unroll
        for (int j = 0; j < 8; j++) tmp[j] = S[(t8 + j) * 136 + d];
        *(uint4*)(VT + ((size_t)(bh * 128 + d)) * 2048 + tc * 64 + t8) = *(uint4*)tmp;
    }
}

// ---------------------------------------------------------------------------
// Stage 5: causal flash attention v9: round-9 internals (4 waves x 16 q-rows,
// KVBLK=64, K/V double-buffered + XOR-swizzled, T13 defer-max) + XCD-affinity
// block mapping. r10 measured FETCH = 487MB = 8 XCDs x 32MB KV x 2 (KVBLK=32
// re-read doubling); r7 = 257MB = 8 x 32MB at KVBLK=64 -> every XCD streamed
// ALL heads' K/V through its private 4MB L2. Fix: 1D grid, bh%8 == bid%8
// (= XCD under round-robin dispatch) so each XCD serves 4 heads = 4MB KV,
// fitting its L2. Attn internals byte-identical to the 396us round-9 state.
// Closed lines: KVBLK=32 (r10, doubles re-reads); 2-wave/64-row (r6);
// V direct-global (r7, scatter overfetch).
// ---------------------------------------------------------------------------
__global__ __launch_bounds__(256) void attn(const u16* __restrict__ Q,
                                            const u16* __restrict__ Kg,
                                            const u16* __restrict__ VTg,
                                            u16* __restrict__ O) {
    __shared__ u16 Kl[2][64 * 128];     // [buf][key][d], XOR-swizzled
    __shared__ u16 Vt[2][128 * 64];     // [buf][d][key], XOR-swizzled
    __shared__ u16 Pl[4 * 16 * 76];     // per-wave P[q][key], stride 76

    const int tid  = threadIdx.x;
    const int w    = tid >> 6;
    const int lane = tid & 63;
    const int quad = lane >> 4;
    const int l16  = lane & 15;
    // XCD-affinity mapping: bid%8 (XCD) == bh%8; 4 heads per XCD.
    const int bid  = blockIdx.x;        // 0..511
    const int pair = bid >> 5;          // 0..15
    const int bh   = (bid & 7) | (((bid >> 3) & 3) << 3);   // 0..31
    const int b = bh >> 4, h = bh & 15;
    const size_t base = (size_t)bh * 2048 * 128;
    const u16* Qb  = Q + base;
    const u16* Kb  = Kg + base;
    const u16* VTb = VTg + base;        // [128 d][2048 t]
    u16* Plw = Pl + w * 16 * 76;
    const float scale = 0.08838834764831845f;   // 1/sqrt(128)

    const int krow = tid >> 4;
    const int kcol = (((tid & 15) ^ (krow & 7)) * 8);
    const int vrow = w * 8 + (lane >> 3);
    const int vcol = (((lane & 7) ^ (vrow & 7)) * 8);
    const int fx   = (l16 & 7);

    for (int s = 0; s < 2; s++) {
        const int qt   = s ? (31 - pair) : pair;
        const int q0   = qt * 64;
        const int row0 = q0 + w * 16;

        bf16x8 Qf[4];
#pragma unroll
        for (int kk = 0; kk < 4; kk++)
            Qf[kk] = *(const bf16x8*)&Qb[(size_t)(row0 + l16) * 128 + kk * 32 + quad * 8];

        f32x4 Oacc[8];
#pragma unroll
        for (int ni = 0; ni < 8; ni++) Oacc[ni] = (f32x4){0.f, 0.f, 0.f, 0.f};
        float mrow = -1e30f, lrow = 0.f;

        const int nkt = qt + 1;

        __syncthreads();
        {
            const u16* ksrc = Kb + (size_t)krow * 128 + kcol;
            char* kdst = (char*)Kl[0] + w * 1024;
            const u16* vsrc = VTb + (size_t)vrow * 2048 + vcol;
            char* vdst = (char*)Vt[0] + w * 1024;
#pragma unroll
            for (int i = 0; i < 4; i++) {
                gload_lds16(ksrc + (size_t)i * 16 * 128, kdst + i * 4096);
                gload_lds16(vsrc + (size_t)i * 32 * 2048, vdst + i * 4096);
            }
        }

        for (int kt = 0; kt < nkt; kt++) {
            const int kt0 = kt * 64;
            const int cur = kt & 1;
            __syncthreads();

            if (kt + 1 < nkt) {
                const int kt1 = kt0 + 64;
                const u16* ksrc = Kb + (size_t)(kt1 + krow) * 128 + kcol;
                char* kdst = (char*)Kl[cur ^ 1] + w * 1024;
                const u16* vsrc = VTb + (size_t)vrow * 2048 + kt1 + vcol;
                char* vdst = (char*)Vt[cur ^ 1] + w * 1024;
#pragma unroll
                for (int i = 0; i < 4; i++) {
                    gload_lds16(ksrc + (size_t)i * 16 * 128, kdst + i * 4096);
                    gload_lds16(vsrc + (size_t)i * 32 * 2048, vdst + i * 4096);
                }
            }

            const u16* Klc = Kl[cur];
            const u16* Vtc = Vt[cur];

            f32x4 ST[4];
#pragma unroll
            for (int mi = 0; mi < 4; mi++) ST[mi] = (f32x4){0.f, 0.f, 0.f, 0.f};
#pragma unroll
            for (int kk = 0; kk < 4; kk++) {
                const int cb = ((kk * 4 + quad) ^ fx) * 8;
#pragma unroll
                for (int mi = 0; mi < 4; mi++) {
                    bf16x8 Kf = *(const bf16x8*)&Klc[(mi * 16 + l16) * 128 + cb];
                    ST[mi] = MFMA_16x16x32_BF16(Kf, Qf[kk], ST[mi]);
                }
            }

            const bool needs_mask = (kt0 + 63) > row0;
            const int qg = row0 + l16;
            float tmax = -1e30f;
#pragma unroll
            for (int mi = 0; mi < 4; mi++) {
#pragma unroll
                for (int r = 0; r < 4; r++) {
                    float sv = ST[mi][r] * scale;
                    if (needs_mask) {
                        int kg = kt0 + mi * 16 + quad * 4 + r;
                        sv = (kg > qg) ? -1e30f : sv;
                    }
                    ST[mi][r] = sv;
                    tmax = fmaxf(tmax, sv);
                }
            }
            tmax = fmaxf(tmax, __shfl_xor(tmax, 16));
            tmax = fmaxf(tmax, __shfl_xor(tmax, 32));

            if (__any(tmax > mrow + 8.0f)) {
                float mnew  = fmaxf(mrow, tmax);
                float alpha = __expf(mrow - mnew);
                mrow = mnew;
                lrow *= alpha;
                float aRow[4];
#pragma unroll
                for (int r = 0; r < 4; r++) aRow[r] = __shfl(alpha, quad * 4 + r);
#pragma unroll
                for (int ni = 0; ni < 8; ni++) {
#pragma unroll
                    for (int r = 0; r < 4; r++) Oacc[ni][r] *= aRow[r];
                }
            }

            float tsum = 0.f;
#pragma unroll
            for (int mi = 0; mi < 4; mi++) {
#pragma unroll
                for (int r = 0; r < 4; r++) {
                    float p = __expf(ST[mi][r] - mrow);
                    ST[mi][r] = p;
                    tsum += p;
                }
            }
            lrow += tsum;

#pragma unroll
            for (int mi = 0; mi < 4; mi++) {
                ushort4 pk;
                pk.x = f2b(ST[mi][0]); pk.y = f2b(ST[mi][1]);
                pk.z = f2b(ST[mi][2]); pk.w = f2b(ST[mi][3]);
                *(ushort4*)&Plw[l16 * 76 + mi * 16 + quad * 4] = pk;
            }

            bf16x8 Pf[2];
#pragma unroll
            for (int kk = 0; kk < 2; kk++)
                Pf[kk] = *(const bf16x8*)&Plw[l16 * 76 + kk * 32 + quad * 8];
#pragma unroll
            for (int kk = 0; kk < 2; kk++) {
                const int cb = ((kk * 4 + quad) ^ fx) * 8;
#pragma unroll
                for (int ni = 0; ni < 8; ni++) {
                    bf16x8 Vf = *(const bf16x8*)&Vtc[(ni * 16 + l16) * 64 + cb];
                    Oacc[ni] = MFMA_16x16x32_BF16(Pf[kk], Vf, Oacc[ni]);
                }
            }
        }

        lrow += __shfl_xor(lrow, 16);
        lrow += __shfl_xor(lrow, 32);
        float inv = 1.0f / lrow;
        float iRow[4];
#pragma unroll
        for (int r = 0; r < 4; r++) iRow[r] = __shfl(inv, quad * 4 + r);

#pragma unroll
        for (int r = 0; r < 4; r++) {
            int t = row0 + quad * 4 + r;
            size_t rowb = ((size_t)(b * 2048 + t)) * 2048 + (size_t)(h * 128);
#pragma unroll
            for (int ni = 0; ni < 8; ni++)
                O[rowb + ni * 16 + l16] = f2b(Oacc[ni][r] * iRow[r]);
        }
    }
}

// ---------------------------------------------------------------------------
extern "C" void kernel_launch(void* const* d_in, const int* in_sizes, int n_in,
                              void* d_out, int out_size, void* d_ws, size_t ws_size,
                              hipStream_t stream) {
    const float* x  = (const float*)d_in[0];
    const float* wq = (const float*)d_in[1];
    const float* wp = (const float*)d_in[2];

    char* ws = (char*)d_ws;
    u16* xb   = (u16*)(ws + 0);            // 16,777,216 B
    u16* wqb  = (u16*)(ws + 16777216);     // 25,165,824 B
    u16* wpb  = (u16*)(ws + 41943040);     //  8,388,608 B
    u16* qkvb = (u16*)(ws + 50331648);     // 50,331,648 B
    u16* Qr   = (u16*)(ws + 100663296);    // 16,777,216 B
    u16* Kr   = (u16*)(ws + 117440512);    // 16,777,216 B
    u16* VTt  = (u16*)(ws + 134217728);    // 16,777,216 B (V^T, [B,H,Dh,T])
    u16* Ob   = (u16*)(ws + 50331648);     // overlays qkvb (dead after rope/vtrans)
    if (ws_size < 150994944) return;

    cast3<<<2048, 256, 0, stream>>>(x, wq, wp, xb, wqb, wpb);
    gemm_bt<1><<<dim3(48, 32), 256, 0, stream>>>(xb, wqb, qkvb, 4096, 6144, 2048);
    rope_qk<<<4096, 256, 0, stream>>>(qkvb, Qr, Kr);
    vtrans<<<dim3(32, 32), 256, 0, stream>>>(qkvb, VTt);
    attn<<<512, 256, 0, stream>>>(Qr, Kr, VTt, Ob);
    gemm_bt<0><<<dim3(16, 32), 256, 0, stream>>>(Ob, wpb, (float*)d_out, 4096, 2048, 2048);
}